// Round 16
// baseline (220.633 us; speedup 1.0000x reference)
//
#include <hip/hip_runtime.h>
#include <math.h>

#define N_NODES 100000
#define N_EDGES 1600000
#define KC 8                      // lanes per node in aggregates
#define KSH 3
#define NBUK 391                  // buckets of 256 nodes (dst >> 8)
#define NCHUNK 256                // scatter/hist chunk blocks
#define CPE 6250                  // edges per chunk (256*6250 = 1.6M exact)
#define M_CNT (NBUK * NCHUNK)     // 100096
#define SCB 512
#define NSC ((M_CNT + SCB - 1) / SCB)   // 196

// ---------------------------------------------------------------------------
__device__ __forceinline__ unsigned bf16_rne(float x) {
    unsigned u = __float_as_uint(x);
    return (u + 0x7FFFu + ((u >> 16) & 1u)) >> 16;
}

// ---------------------------------------------------------------------------
// K1 (block = 1024): blocks [0,NCHUNK) histogram dst-buckets (LDS atomics);
// blocks [NCHUNK, NCHUNK+1563) run the layer-1 transform (64 nodes/block).
// Y output is PLANAR: YA[n*8+o] (features 0-7), YB[n*8+o-8] (features 8-15),
// each word = bf16(Y0) | bf16(Y1)<<16. 3.2 MB per half -> fits per-XCD L2.
__global__ __launch_bounds__(1024)
void fused_hist_transform(const float* __restrict__ X,
                          const float* __restrict__ W,
                          const float* __restrict__ root,
                          const float* __restrict__ bias,
                          unsigned* __restrict__ YA, unsigned* __restrict__ YB,
                          float* __restrict__ R,
                          const int* __restrict__ dst,
                          int* __restrict__ counts) {
    int t = threadIdx.x;
    if (blockIdx.x < NCHUNK) {
        __shared__ int h[NBUK];
        for (int i = t; i < NBUK; i += 1024) h[i] = 0;
        __syncthreads();
        int c = blockIdx.x;
        const int* dp = dst + c * CPE;
        for (int j = t; j < CPE; j += 1024) atomicAdd(&h[dp[j] >> 8], 1);
        __syncthreads();
        for (int i = t; i < NBUK; i += 1024) counts[i * NCHUNK + c] = h[i];
    } else {
        __shared__ float sW0[48 * 16];
        __shared__ float sWd[48 * 16];
        __shared__ float sR[48 * 16];
        __shared__ float sB[16];
        int bid = blockIdx.x - NCHUNK;
        for (int i = t; i < 48 * 16; i += 1024) {
            float w0 = W[i];
            float w1 = W[48 * 16 + i];
            sW0[i] = w0;
            sWd[i] = w1 - w0;
            sR[i]  = root[i];
        }
        if (t < 16) sB[t] = bias[t];
        __syncthreads();

        int idx = bid * 1024 + t;
        int n = idx >> 4;
        int o = idx & 15;
        if (n >= N_NODES) return;

        const float* xr = X + (long)n * 48;
        float a0 = 0.0f, a1 = 0.0f, ar = 0.0f;
        for (int f = 0; f < 48; ++f) {
            float xv = xr[f];
            a0 = fmaf(xv, sW0[f * 16 + o], a0);
            a1 = fmaf(xv, sWd[f * 16 + o], a1);
            ar = fmaf(xv, sR[f * 16 + o], ar);
        }
        unsigned w = bf16_rne(a0) | (bf16_rne(a1) << 16);
        if (o < 8) YA[n * 8 + o] = w;
        else       YB[n * 8 + (o - 8)] = w;
        R[idx] = ar + sB[o];
    }
}

// ---------------------------------------------------------------------------
// Hierarchical exclusive scan of counts[M_CNT] (3 parallel kernels).
__global__ __launch_bounds__(SCB)
void scan_blocksum(const int* __restrict__ a, int* __restrict__ bsum) {
    __shared__ int s[SCB];
    int t = threadIdx.x;
    int i = blockIdx.x * SCB + t;
    s[t] = (i < M_CNT) ? a[i] : 0;
    __syncthreads();
    for (int off = SCB / 2; off > 0; off >>= 1) {
        if (t < off) s[t] += s[t + off];
        __syncthreads();
    }
    if (t == 0) bsum[blockIdx.x] = s[0];
}

__global__ __launch_bounds__(256)
void scan_bsum(int* __restrict__ bsum) {
    __shared__ int s[256];
    int t = threadIdx.x;
    int v = (t < NSC) ? bsum[t] : 0;
    s[t] = v;
    __syncthreads();
    for (int off = 1; off < 256; off <<= 1) {
        int x = (t >= off) ? s[t - off] : 0;
        __syncthreads();
        s[t] += x;
        __syncthreads();
    }
    if (t < NSC) bsum[t] = s[t] - v;  // exclusive
}

__global__ __launch_bounds__(SCB)
void scan_write(int* __restrict__ a, const int* __restrict__ bsum) {
    __shared__ int s[SCB];
    int t = threadIdx.x;
    int i = blockIdx.x * SCB + t;
    int v = (i < M_CNT) ? a[i] : 0;
    s[t] = v;
    __syncthreads();
    for (int off = 1; off < SCB; off <<= 1) {
        int x = (t >= off) ? s[t - off] : 0;
        __syncthreads();
        s[t] += x;
        __syncthreads();
    }
    if (i < M_CNT) a[i] = bsum[blockIdx.x] + s[t] - v;  // exclusive
}

// ---------------------------------------------------------------------------
// K3 (block = 1024): in-LDS counting sort per chunk, then COALESCED writes.
__global__ __launch_bounds__(1024)
void scatter_edges(const int* __restrict__ src, const int* __restrict__ dst,
                   const float* __restrict__ u,
                   const int* __restrict__ offsets,
                   unsigned* __restrict__ pk, unsigned char* __restrict__ dl) {
    __shared__ unsigned upk[CPE];        // unsorted pk
    __shared__ unsigned short ubuk[CPE]; // bucket per edge
    __shared__ unsigned char udl[CPE];   // unsorted dl
    __shared__ unsigned spk[CPE];        // sorted pk
    __shared__ unsigned char sdl[CPE];   // sorted dl
    __shared__ int ls[NBUK + 1];         // local exclusive offsets
    __shared__ int lcur[NBUK];           // local cursors
    __shared__ int gbase[NBUK];          // cur_global[b] - ls[b]
    __shared__ int sc[SCB];              // scan temp (512)

    int t = threadIdx.x, c = blockIdx.x;

    for (int i = t; i < NBUK; i += 1024) lcur[i] = 0;   // lcur doubles as hist
    __syncthreads();
    for (int j = t; j < CPE; j += 1024) {
        int e = c * CPE + j;
        int d = dst[e];
        float uu = u[e];
        uu = uu < 0.0f ? 0.0f : (uu > 1.0f ? 1.0f : uu);
        int u15 = (int)fmaf(uu, 32767.0f, 0.5f);
        upk[j] = (unsigned)src[e] | ((unsigned)u15 << 17);
        udl[j] = (unsigned char)(d & 255);
        int b = d >> 8;
        ubuk[j] = (unsigned short)b;
        atomicAdd(&lcur[b], 1);
    }
    __syncthreads();

    int v = 0;
    if (t < SCB) {
        v = (t < NBUK) ? lcur[t] : 0;
        sc[t] = v;
    }
    __syncthreads();
    for (int off = 1; off < SCB; off <<= 1) {
        int x = 0;
        if (t < SCB && t >= off) x = sc[t - off];
        __syncthreads();
        if (t < SCB) sc[t] += x;
        __syncthreads();
    }
    if (t < NBUK) {
        int ex = sc[t] - v;
        ls[t] = ex;
        lcur[t] = ex;
        gbase[t] = offsets[t * NCHUNK + c] - ex;
    }
    if (t == 0) ls[NBUK] = CPE;
    __syncthreads();

    for (int j = t; j < CPE; j += 1024) {
        int b = ubuk[j];
        int p = atomicAdd(&lcur[b], 1);
        spk[p] = upk[j];
        sdl[p] = udl[j];
    }
    __syncthreads();

    for (int j = t; j < CPE; j += 1024) {
        int lo = 0, hi = NBUK;
        while (hi - lo > 1) {
            int mid = (lo + hi) >> 1;
            if (ls[mid] <= j) lo = mid; else hi = mid;
        }
        int g = gbase[lo] + j;
        pk[g] = spk[j];
        dl[g] = sdl[j];
    }
}

// ---------------------------------------------------------------------------
// K4: one block per bucket; group the bucket's edges by node -> dense CSR.
__global__ __launch_bounds__(256)
void group_edges(const int* __restrict__ offsets,
                 const unsigned* __restrict__ pk_in,
                 const unsigned char* __restrict__ dl,
                 unsigned* __restrict__ pk_out,
                 int* __restrict__ rowptr) {
    __shared__ int h[256];
    __shared__ int pre[256];
    int b = blockIdx.x, t = threadIdx.x;
    int beg = offsets[b * NCHUNK];
    int end = (b + 1 < NBUK) ? offsets[(b + 1) * NCHUNK] : N_EDGES;
    h[t] = 0;
    __syncthreads();
    for (int j = beg + t; j < end; j += 256) atomicAdd(&h[dl[j]], 1);
    __syncthreads();
    int cntv = h[t];
    pre[t] = cntv;
    __syncthreads();
    for (int off = 1; off < 256; off <<= 1) {
        int x = (t >= off) ? pre[t - off] : 0;
        __syncthreads();
        pre[t] += x;
        __syncthreads();
    }
    int ex = pre[t] - cntv;   // exclusive local offset of node (b<<8)+t
    int node0 = b << 8;
    if (node0 + t < N_NODES) rowptr[node0 + t] = beg + ex;
    if (b == 0 && t == 0) rowptr[N_NODES] = N_EDGES;
    __syncthreads();
    h[t] = ex;                // reuse as cursor
    __syncthreads();
    for (int j = beg + t; j < end; j += 256) {
        int loc = dl[j];
        int pos = atomicAdd(&h[loc], 1);
        pk_out[beg + pos] = pk_in[j];
    }
}

// ---------------------------------------------------------------------------
// Half-table accumulation: lane h gathers 4 B (one feature pair word) per
// edge from a 3.2 MB planar table (L2-resident per XCD). Unroll 4.
__device__ __forceinline__ float half_accum(int beg, int end, int h,
                                            const unsigned* __restrict__ csr,
                                            const unsigned* __restrict__ Y) {
    float acc = 0.0f;
    int j = beg;
    for (; j + 3 < end; j += 4) {
        unsigned p0 = csr[j], p1 = csr[j + 1], p2 = csr[j + 2], p3 = csr[j + 3];
        unsigned w0 = Y[(size_t)(p0 & 0x1FFFFu) * 8 + h];
        unsigned w1 = Y[(size_t)(p1 & 0x1FFFFu) * 8 + h];
        unsigned w2 = Y[(size_t)(p2 & 0x1FFFFu) * 8 + h];
        unsigned w3 = Y[(size_t)(p3 & 0x1FFFFu) * 8 + h];
        float u0 = (float)(p0 >> 17) * (1.0f / 32767.0f);
        float u1 = (float)(p1 >> 17) * (1.0f / 32767.0f);
        float u2 = (float)(p2 >> 17) * (1.0f / 32767.0f);
        float u3 = (float)(p3 >> 17) * (1.0f / 32767.0f);
        acc += fmaf(u0, __uint_as_float(w0 & 0xFFFF0000u), __uint_as_float(w0 << 16));
        acc += fmaf(u1, __uint_as_float(w1 & 0xFFFF0000u), __uint_as_float(w1 << 16));
        acc += fmaf(u2, __uint_as_float(w2 & 0xFFFF0000u), __uint_as_float(w2 << 16));
        acc += fmaf(u3, __uint_as_float(w3 & 0xFFFF0000u), __uint_as_float(w3 << 16));
    }
    for (; j < end; ++j) {
        unsigned p0 = csr[j];
        unsigned w0 = Y[(size_t)(p0 & 0x1FFFFu) * 8 + h];
        float u0 = (float)(p0 >> 17) * (1.0f / 32767.0f);
        acc += fmaf(u0, __uint_as_float(w0 & 0xFFFF0000u), __uint_as_float(w0 << 16));
    }
    return acc;
}

// ---------------------------------------------------------------------------
// Aggregate layer 1 + ELU + layer-2 transform fused (planar half-tables).
// Lane h owns features h and h+8.
__global__ __launch_bounds__(256)
void aggregate_elu_transform(const int* __restrict__ rowptr,
                             const unsigned* __restrict__ csr,
                             const unsigned* __restrict__ YA1,
                             const unsigned* __restrict__ YB1,
                             const float* __restrict__ R1,
                             const float* __restrict__ W2,
                             const float* __restrict__ root2,
                             const float* __restrict__ b2,
                             unsigned* __restrict__ YA2,
                             unsigned* __restrict__ YB2,
                             float* __restrict__ R2) {
    __shared__ float sW0[16 * 16];
    __shared__ float sWd[16 * 16];
    __shared__ float sR[16 * 16];
    __shared__ float sB[16];
    int t = threadIdx.x;
    {
        float w0 = W2[t];
        float w1 = W2[256 + t];
        sW0[t] = w0;
        sWd[t] = w1 - w0;
        sR[t]  = root2[t];
    }
    if (t < 16) sB[t] = b2[t];
    __syncthreads();

    int g = blockIdx.x * 256 + t;
    int n = g >> KSH;
    int h = g & (KC - 1);
    int beg = rowptr[n], end = rowptr[n + 1];
    int deg = end - beg;

    float sA = half_accum(beg, end, h, csr, YA1);   // feature h
    float sBv = half_accum(beg, end, h, csr, YB1);  // feature h+8
    float inv = 1.0f / (deg > 0 ? (float)deg : 1.0f);

    float v0 = fmaf(sA, inv, R1[n * 16 + h]);
    float v1 = fmaf(sBv, inv, R1[n * 16 + 8 + h]);
    v0 = v0 > 0.0f ? v0 : expm1f(v0);
    v1 = v1 > 0.0f ? v1 : expm1f(v1);

    // rebuild full H row in every lane via octet shuffles
    int base = (t & 63) & ~7;
    float h16[16];
#pragma unroll
    for (int k = 0; k < 8; ++k) {
        h16[k]     = __shfl(v0, base + k, 64);
        h16[8 + k] = __shfl(v1, base + k, 64);
    }

    // layer-2 transform: this lane's output features h and h+8
    float y0 = 0.0f, y1 = 0.0f, yr = 0.0f;   // feature h
    float z0 = 0.0f, z1 = 0.0f, zr = 0.0f;   // feature h+8
#pragma unroll
    for (int f = 0; f < 16; ++f) {
        float hv = h16[f];
        y0 = fmaf(hv, sW0[f * 16 + h], y0);
        y1 = fmaf(hv, sWd[f * 16 + h], y1);
        yr = fmaf(hv, sR[f * 16 + h],  yr);
        z0 = fmaf(hv, sW0[f * 16 + 8 + h], z0);
        z1 = fmaf(hv, sWd[f * 16 + 8 + h], z1);
        zr = fmaf(hv, sR[f * 16 + 8 + h],  zr);
    }
    YA2[g] = bf16_rne(y0) | (bf16_rne(y1) << 16);   // g == n*8+h: coalesced
    YB2[g] = bf16_rne(z0) | (bf16_rne(z1) << 16);
    R2[n * 16 + h]     = yr + sB[h];
    R2[n * 16 + 8 + h] = zr + sB[8 + h];
}

// ---------------------------------------------------------------------------
// Aggregate layer 2 + log-softmax (planar half-tables).
__global__ __launch_bounds__(256)
void aggregate_logsoftmax(const int* __restrict__ rowptr,
                          const unsigned* __restrict__ csr,
                          const unsigned* __restrict__ YA,
                          const unsigned* __restrict__ YB,
                          const float* __restrict__ R,
                          float* __restrict__ out) {
    int g = blockIdx.x * 256 + threadIdx.x;
    int n = g >> KSH;
    int h = g & (KC - 1);
    int beg = rowptr[n], end = rowptr[n + 1];
    int deg = end - beg;

    float sA = half_accum(beg, end, h, csr, YA);
    float sBv = half_accum(beg, end, h, csr, YB);
    float inv = 1.0f / (deg > 0 ? (float)deg : 1.0f);

    float v0 = fmaf(sA, inv, R[n * 16 + h]);
    float v1 = fmaf(sBv, inv, R[n * 16 + 8 + h]);

    float m = fmaxf(v0, v1);
#pragma unroll
    for (int mask = 1; mask <= 4; mask <<= 1) m = fmaxf(m, __shfl_xor(m, mask));
    float s = expf(v0 - m) + expf(v1 - m);
#pragma unroll
    for (int mask = 1; mask <= 4; mask <<= 1) s += __shfl_xor(s, mask);
    float lse = m + logf(s);

    out[n * 16 + h]     = v0 - lse;
    out[n * 16 + 8 + h] = v1 - lse;
}

// ---------------------------------------------------------------------------
extern "C" void kernel_launch(void* const* d_in, const int* in_sizes, int n_in,
                              void* d_out, int out_size, void* d_ws, size_t ws_size,
                              hipStream_t stream) {
    const float* x         = (const float*)d_in[0];
    const float* edge_attr = (const float*)d_in[1];
    const int*   edge_idx  = (const int*)d_in[2];
    const float* W1        = (const float*)d_in[3];
    const float* root1     = (const float*)d_in[4];
    const float* b1        = (const float*)d_in[5];
    const float* W2        = (const float*)d_in[6];
    const float* root2     = (const float*)d_in[7];
    const float* b2        = (const float*)d_in[8];
    float* out = (float*)d_out;

    const int* src = edge_idx;
    const int* dst = edge_idx + N_EDGES;

    // workspace layout (byte offsets, 16B aligned), total ~40.8 MB
    char* ws = (char*)d_ws;
    unsigned*      pk_in   = (unsigned*)(ws);                  //  6,400,000
    unsigned*      pk_out  = (unsigned*)(ws + 6400000);        //  6,400,000
    unsigned char* dl      = (unsigned char*)(ws + 12800000);  //  1,600,000
    int*           counts  = (int*)(ws + 14400000);            //    400,384
    int*           rowptr  = (int*)(ws + 14800384);            //    400,016
    unsigned*      YA1     = (unsigned*)(ws + 15200400);       //  3,200,000
    unsigned*      YB1     = (unsigned*)(ws + 18400400);       //  3,200,000
    unsigned*      YA2     = (unsigned*)(ws + 21600400);       //  3,200,000
    unsigned*      YB2     = (unsigned*)(ws + 24800400);       //  3,200,000
    float*         R1      = (float*)(ws + 28000400);          //  6,400,000
    float*         R2      = (float*)(ws + 34400400);          //  6,400,000
    int*           bsum    = (int*)(ws + 40800400);            //        784

    dim3 gK1(NCHUNK + (N_NODES * 16 + 1023) / 1024);   // 256 + 1563
    dim3 gAgg((N_NODES * KC) / 256);                   // 3125 exact

    fused_hist_transform<<<gK1, 1024, 0, stream>>>(
        x, W1, root1, b1, YA1, YB1, R1, dst, counts);
    scan_blocksum<<<NSC, SCB, 0, stream>>>(counts, bsum);
    scan_bsum<<<1, 256, 0, stream>>>(bsum);
    scan_write<<<NSC, SCB, 0, stream>>>(counts, bsum);
    scatter_edges<<<NCHUNK, 1024, 0, stream>>>(src, dst, edge_attr,
                                               counts, pk_in, dl);
    group_edges<<<NBUK, 256, 0, stream>>>(counts, pk_in, dl, pk_out, rowptr);

    aggregate_elu_transform<<<gAgg, 256, 0, stream>>>(
        rowptr, pk_out, YA1, YB1, R1, W2, root2, b2, YA2, YB2, R2);

    aggregate_logsoftmax<<<gAgg, 256, 0, stream>>>(
        rowptr, pk_out, YA2, YB2, R2, out);
}

// Round 17
// 209.992 us; speedup vs baseline: 1.0507x; 1.0507x over previous
//
#include <hip/hip_runtime.h>
#include <math.h>

#define N_NODES 100000
#define N_EDGES 1600000
#define KC 8                      // lanes per node in aggregates
#define KSH 3
#define NBUK 391                  // buckets of 256 nodes (dst >> 8)
#define NCHUNK 256                // scatter/hist chunk blocks
#define CPE 6250                  // edges per chunk (256*6250 = 1.6M exact)
#define M_CNT (NBUK * NCHUNK)     // 100096
#define SCB 512
#define NSC ((M_CNT + SCB - 1) / SCB)   // 196

#define NTL(p) __builtin_nontemporal_load(p)

// ---------------------------------------------------------------------------
__device__ __forceinline__ unsigned bf16_rne(float x) {
    unsigned u = __float_as_uint(x);
    return (u + 0x7FFFu + ((u >> 16) & 1u)) >> 16;
}

// accumulate 4 packed (bf16,bf16) words with weight uu
__device__ __forceinline__ void acc4(float* acc, uint4 w, float uu) {
    acc[0] += fmaf(uu, __uint_as_float(w.x & 0xFFFF0000u), __uint_as_float(w.x << 16));
    acc[1] += fmaf(uu, __uint_as_float(w.y & 0xFFFF0000u), __uint_as_float(w.y << 16));
    acc[2] += fmaf(uu, __uint_as_float(w.z & 0xFFFF0000u), __uint_as_float(w.z << 16));
    acc[3] += fmaf(uu, __uint_as_float(w.w & 0xFFFF0000u), __uint_as_float(w.w << 16));
}

// accumulate one edge (pk = src | u15<<17) from packed-bf16 Y table
__device__ __forceinline__ void edge_accum(unsigned pk,
                                           const uint4* __restrict__ YPH,
                                           float acc[16]) {
    float uu = (float)(pk >> 17) * (1.0f / 32767.0f);
    const uint4* yp = YPH + (size_t)(pk & 0x1FFFFu) * 4;
    uint4 w0 = yp[0], w1 = yp[1], w2 = yp[2], w3 = yp[3];
    acc4(acc + 0, w0, uu);
    acc4(acc + 4, w1, uu);
    acc4(acc + 8, w2, uu);
    acc4(acc + 12, w3, uu);
}

// two edges, loads grouped ahead of FMAs for MLP
__device__ __forceinline__ void edge_accum2(unsigned p0, unsigned p1,
                                            const uint4* __restrict__ YPH,
                                            float acc[16]) {
    float u0 = (float)(p0 >> 17) * (1.0f / 32767.0f);
    float u1 = (float)(p1 >> 17) * (1.0f / 32767.0f);
    const uint4* a = YPH + (size_t)(p0 & 0x1FFFFu) * 4;
    const uint4* b = YPH + (size_t)(p1 & 0x1FFFFu) * 4;
    uint4 w0 = a[0], w1 = a[1], w2 = a[2], w3 = a[3];
    uint4 v0 = b[0], v1 = b[1], v2 = b[2], v3 = b[3];
    acc4(acc + 0, w0, u0);
    acc4(acc + 4, w1, u0);
    acc4(acc + 8, w2, u0);
    acc4(acc + 12, w3, u0);
    acc4(acc + 0, v0, u1);
    acc4(acc + 4, v1, u1);
    acc4(acc + 8, v2, u1);
    acc4(acc + 12, v3, u1);
}

// ---------------------------------------------------------------------------
// K1 (block = 1024): blocks [0,NCHUNK) histogram dst-buckets (LDS atomics);
// blocks [NCHUNK, NCHUNK+1563) run the layer-1 transform (64 nodes/block).
__global__ __launch_bounds__(1024)
void fused_hist_transform(const float* __restrict__ X,
                          const float* __restrict__ W,
                          const float* __restrict__ root,
                          const float* __restrict__ bias,
                          unsigned* __restrict__ YPH, float* __restrict__ R,
                          const int* __restrict__ dst,
                          int* __restrict__ counts) {
    int t = threadIdx.x;
    if (blockIdx.x < NCHUNK) {
        __shared__ int h[NBUK];
        for (int i = t; i < NBUK; i += 1024) h[i] = 0;
        __syncthreads();
        int c = blockIdx.x;
        const int* dp = dst + c * CPE;
        for (int j = t; j < CPE; j += 1024) atomicAdd(&h[NTL(dp + j) >> 8], 1);
        __syncthreads();
        for (int i = t; i < NBUK; i += 1024) counts[i * NCHUNK + c] = h[i];
    } else {
        __shared__ float sW0[48 * 16];
        __shared__ float sWd[48 * 16];
        __shared__ float sR[48 * 16];
        __shared__ float sB[16];
        int bid = blockIdx.x - NCHUNK;
        for (int i = t; i < 48 * 16; i += 1024) {
            float w0 = W[i];
            float w1 = W[48 * 16 + i];
            sW0[i] = w0;
            sWd[i] = w1 - w0;
            sR[i]  = root[i];
        }
        if (t < 16) sB[t] = bias[t];
        __syncthreads();

        int idx = bid * 1024 + t;
        int n = idx >> 4;
        int o = idx & 15;
        if (n >= N_NODES) return;

        const float* xr = X + (long)n * 48;
        float a0 = 0.0f, a1 = 0.0f, ar = 0.0f;
        for (int f = 0; f < 48; ++f) {
            float xv = xr[f];
            a0 = fmaf(xv, sW0[f * 16 + o], a0);
            a1 = fmaf(xv, sWd[f * 16 + o], a1);
            ar = fmaf(xv, sR[f * 16 + o], ar);
        }
        YPH[idx] = bf16_rne(a0) | (bf16_rne(a1) << 16);
        R[idx]   = ar + sB[o];
    }
}

// ---------------------------------------------------------------------------
// Hierarchical exclusive scan of counts[M_CNT] (3 parallel kernels).
__global__ __launch_bounds__(SCB)
void scan_blocksum(const int* __restrict__ a, int* __restrict__ bsum) {
    __shared__ int s[SCB];
    int t = threadIdx.x;
    int i = blockIdx.x * SCB + t;
    s[t] = (i < M_CNT) ? a[i] : 0;
    __syncthreads();
    for (int off = SCB / 2; off > 0; off >>= 1) {
        if (t < off) s[t] += s[t + off];
        __syncthreads();
    }
    if (t == 0) bsum[blockIdx.x] = s[0];
}

__global__ __launch_bounds__(256)
void scan_bsum(int* __restrict__ bsum) {
    __shared__ int s[256];
    int t = threadIdx.x;
    int v = (t < NSC) ? bsum[t] : 0;
    s[t] = v;
    __syncthreads();
    for (int off = 1; off < 256; off <<= 1) {
        int x = (t >= off) ? s[t - off] : 0;
        __syncthreads();
        s[t] += x;
        __syncthreads();
    }
    if (t < NSC) bsum[t] = s[t] - v;  // exclusive
}

__global__ __launch_bounds__(SCB)
void scan_write(int* __restrict__ a, const int* __restrict__ bsum) {
    __shared__ int s[SCB];
    int t = threadIdx.x;
    int i = blockIdx.x * SCB + t;
    int v = (i < M_CNT) ? a[i] : 0;
    s[t] = v;
    __syncthreads();
    for (int off = 1; off < SCB; off <<= 1) {
        int x = (t >= off) ? s[t - off] : 0;
        __syncthreads();
        s[t] += x;
        __syncthreads();
    }
    if (i < M_CNT) a[i] = bsum[blockIdx.x] + s[t] - v;  // exclusive
}

// ---------------------------------------------------------------------------
// K3 (block = 1024): in-LDS counting sort per chunk, then COALESCED writes.
__global__ __launch_bounds__(1024)
void scatter_edges(const int* __restrict__ src, const int* __restrict__ dst,
                   const float* __restrict__ u,
                   const int* __restrict__ offsets,
                   unsigned* __restrict__ pk, unsigned char* __restrict__ dl) {
    __shared__ unsigned upk[CPE];        // unsorted pk
    __shared__ unsigned short ubuk[CPE]; // bucket per edge
    __shared__ unsigned char udl[CPE];   // unsorted dl
    __shared__ unsigned spk[CPE];        // sorted pk
    __shared__ unsigned char sdl[CPE];   // sorted dl
    __shared__ int ls[NBUK + 1];         // local exclusive offsets
    __shared__ int lcur[NBUK];           // local cursors
    __shared__ int gbase[NBUK];          // cur_global[b] - ls[b]
    __shared__ int sc[SCB];              // scan temp (512)

    int t = threadIdx.x, c = blockIdx.x;

    // pass 1: load edges, compute pk/dl/buk, count per bucket
    for (int i = t; i < NBUK; i += 1024) lcur[i] = 0;   // lcur doubles as hist
    __syncthreads();
    for (int j = t; j < CPE; j += 1024) {
        int e = c * CPE + j;
        int d = NTL(dst + e);
        float uu = NTL(u + e);
        uu = uu < 0.0f ? 0.0f : (uu > 1.0f ? 1.0f : uu);
        int u15 = (int)fmaf(uu, 32767.0f, 0.5f);
        upk[j] = (unsigned)NTL(src + e) | ((unsigned)u15 << 17);
        udl[j] = (unsigned char)(d & 255);
        int b = d >> 8;
        ubuk[j] = (unsigned short)b;
        atomicAdd(&lcur[b], 1);
    }
    __syncthreads();

    // block scan of 391 counts -> ls (exclusive); all threads hit barriers
    int v = 0;
    if (t < SCB) {
        v = (t < NBUK) ? lcur[t] : 0;
        sc[t] = v;
    }
    __syncthreads();
    for (int off = 1; off < SCB; off <<= 1) {
        int x = 0;
        if (t < SCB && t >= off) x = sc[t - off];
        __syncthreads();
        if (t < SCB) sc[t] += x;
        __syncthreads();
    }
    if (t < NBUK) {
        int ex = sc[t] - v;
        ls[t] = ex;
        lcur[t] = ex;
        gbase[t] = offsets[t * NCHUNK + c] - ex;
    }
    if (t == 0) ls[NBUK] = CPE;
    __syncthreads();

    // pass 2: LDS->LDS counting sort into bucket order
    for (int j = t; j < CPE; j += 1024) {
        int b = ubuk[j];
        int p = atomicAdd(&lcur[b], 1);
        spk[p] = upk[j];
        sdl[p] = udl[j];
    }
    __syncthreads();

    // pass 3: coalesced write-out; bucket of slot j via binary search in ls
    for (int j = t; j < CPE; j += 1024) {
        int lo = 0, hi = NBUK;
        while (hi - lo > 1) {
            int mid = (lo + hi) >> 1;
            if (ls[mid] <= j) lo = mid; else hi = mid;
        }
        int g = gbase[lo] + j;
        pk[g] = spk[j];
        dl[g] = sdl[j];
    }
}

// ---------------------------------------------------------------------------
// K4: one block per bucket; group the bucket's edges by node -> dense CSR.
__global__ __launch_bounds__(256)
void group_edges(const int* __restrict__ offsets,
                 const unsigned* __restrict__ pk_in,
                 const unsigned char* __restrict__ dl,
                 unsigned* __restrict__ pk_out,
                 int* __restrict__ rowptr) {
    __shared__ int h[256];
    __shared__ int pre[256];
    int b = blockIdx.x, t = threadIdx.x;
    int beg = offsets[b * NCHUNK];
    int end = (b + 1 < NBUK) ? offsets[(b + 1) * NCHUNK] : N_EDGES;
    h[t] = 0;
    __syncthreads();
    for (int j = beg + t; j < end; j += 256) atomicAdd(&h[NTL(dl + j)], 1);
    __syncthreads();
    int cntv = h[t];
    pre[t] = cntv;
    __syncthreads();
    for (int off = 1; off < 256; off <<= 1) {
        int x = (t >= off) ? pre[t - off] : 0;
        __syncthreads();
        pre[t] += x;
        __syncthreads();
    }
    int ex = pre[t] - cntv;   // exclusive local offset of node (b<<8)+t
    int node0 = b << 8;
    if (node0 + t < N_NODES) rowptr[node0 + t] = beg + ex;
    if (b == 0 && t == 0) rowptr[N_NODES] = N_EDGES;
    __syncthreads();
    h[t] = ex;                // reuse as cursor
    __syncthreads();
    for (int j = beg + t; j < end; j += 256) {
        int loc = dl[j];
        int pos = atomicAdd(&h[loc], 1);
        pk_out[beg + pos] = pk_in[j];
    }
}

// ---------------------------------------------------------------------------
// Aggregate layer 1 + ELU + layer-2 transform fused. KC lanes per node read
// the node's CSR range streamed (nontemporal — zero reuse, protect L2 for
// the Y-table gathers); butterfly leaves full acc in every lane.
__global__ __launch_bounds__(256)
void aggregate_elu_transform(const int* __restrict__ rowptr,
                             const unsigned* __restrict__ csr,
                             const uint4* __restrict__ YPH1,
                             const float* __restrict__ R1,
                             const float* __restrict__ W2,
                             const float* __restrict__ root2,
                             const float* __restrict__ b2,
                             unsigned* __restrict__ YPH2,
                             float* __restrict__ R2) {
    __shared__ float sW0[16 * 16];
    __shared__ float sWd[16 * 16];
    __shared__ float sR[16 * 16];
    __shared__ float sB[16];
    int t = threadIdx.x;
    {
        float w0 = W2[t];
        float w1 = W2[256 + t];
        sW0[t] = w0;
        sWd[t] = w1 - w0;
        sR[t]  = root2[t];
    }
    if (t < 16) sB[t] = b2[t];
    __syncthreads();

    int g = blockIdx.x * 256 + t;
    int n = g >> KSH;
    int h = g & (KC - 1);
    int beg = rowptr[n], end = rowptr[n + 1];
    int deg = end - beg;

    float acc[16];
#pragma unroll
    for (int i = 0; i < 16; ++i) acc[i] = 0.0f;
    int j = beg + h;
    for (; j + KC < end; j += 2 * KC)
        edge_accum2(NTL(csr + j), NTL(csr + j + KC), YPH1, acc);
    if (j < end) edge_accum(NTL(csr + j), YPH1, acc);

#pragma unroll
    for (int mask = 1; mask <= 4; mask <<= 1) {
#pragma unroll
        for (int i = 0; i < 16; ++i) acc[i] += __shfl_xor(acc[i], mask);
    }
    float inv = 1.0f / (deg > 0 ? (float)deg : 1.0f);

    // full H row (ELU'd) in registers
    float h16[16];
    const float4* rp = (const float4*)(R1 + (size_t)n * 16);
#pragma unroll
    for (int q = 0; q < 4; ++q) {
        float4 rr = rp[q];
        float v;
        v = fmaf(acc[4 * q + 0], inv, rr.x); h16[4 * q + 0] = v > 0.0f ? v : expm1f(v);
        v = fmaf(acc[4 * q + 1], inv, rr.y); h16[4 * q + 1] = v > 0.0f ? v : expm1f(v);
        v = fmaf(acc[4 * q + 2], inv, rr.z); h16[4 * q + 2] = v > 0.0f ? v : expm1f(v);
        v = fmaf(acc[4 * q + 3], inv, rr.w); h16[4 * q + 3] = v > 0.0f ? v : expm1f(v);
    }

    // layer-2 transform: this lane's 2 output features o = 2h, 2h+1
    int o0 = 2 * h;
    float a0 = 0.0f, a1 = 0.0f, ar = 0.0f;
    float c0 = 0.0f, c1 = 0.0f, cr = 0.0f;
#pragma unroll
    for (int f = 0; f < 16; ++f) {
        float hv = h16[f];
        a0 = fmaf(hv, sW0[f * 16 + o0], a0);
        a1 = fmaf(hv, sWd[f * 16 + o0], a1);
        ar = fmaf(hv, sR[f * 16 + o0],  ar);
        c0 = fmaf(hv, sW0[f * 16 + o0 + 1], c0);
        c1 = fmaf(hv, sWd[f * 16 + o0 + 1], c1);
        cr = fmaf(hv, sR[f * 16 + o0 + 1],  cr);
    }
    ((uint2*)YPH2)[g] = make_uint2(bf16_rne(a0) | (bf16_rne(a1) << 16),
                                   bf16_rne(c0) | (bf16_rne(c1) << 16));
    ((float2*)R2)[g] = make_float2(ar + sB[o0], cr + sB[o0 + 1]);
}

// ---------------------------------------------------------------------------
// Aggregate layer 2 + log-softmax, CSR streamed (nontemporal).
__global__ __launch_bounds__(256)
void aggregate_logsoftmax(const int* __restrict__ rowptr,
                          const unsigned* __restrict__ csr,
                          const uint4* __restrict__ YPH,
                          const float* __restrict__ R,
                          float* __restrict__ out) {
    int g = blockIdx.x * 256 + threadIdx.x;
    int n = g >> KSH;
    int h = g & (KC - 1);
    int beg = rowptr[n], end = rowptr[n + 1];
    int deg = end - beg;

    float acc[16];
#pragma unroll
    for (int i = 0; i < 16; ++i) acc[i] = 0.0f;
    int j = beg + h;
    for (; j + KC < end; j += 2 * KC)
        edge_accum2(NTL(csr + j), NTL(csr + j + KC), YPH, acc);
    if (j < end) edge_accum(NTL(csr + j), YPH, acc);

#pragma unroll
    for (int mask = 1; mask <= 4; mask <<= 1) {
#pragma unroll
        for (int i = 0; i < 16; ++i) acc[i] += __shfl_xor(acc[i], mask);
    }
    float inv = 1.0f / (deg > 0 ? (float)deg : 1.0f);

    float2 rr = ((const float2*)R)[g];
    float v0 = fmaf(acc[2 * h + 0], inv, rr.x);
    float v1 = fmaf(acc[2 * h + 1], inv, rr.y);

    float m = fmaxf(v0, v1);
#pragma unroll
    for (int mask = 1; mask <= 4; mask <<= 1) m = fmaxf(m, __shfl_xor(m, mask));
    float s = expf(v0 - m) + expf(v1 - m);
#pragma unroll
    for (int mask = 1; mask <= 4; mask <<= 1) s += __shfl_xor(s, mask);
    float lse = m + logf(s);

    ((float2*)out)[g] = make_float2(v0 - lse, v1 - lse);
}

// ---------------------------------------------------------------------------
extern "C" void kernel_launch(void* const* d_in, const int* in_sizes, int n_in,
                              void* d_out, int out_size, void* d_ws, size_t ws_size,
                              hipStream_t stream) {
    const float* x         = (const float*)d_in[0];
    const float* edge_attr = (const float*)d_in[1];
    const int*   edge_idx  = (const int*)d_in[2];
    const float* W1        = (const float*)d_in[3];
    const float* root1     = (const float*)d_in[4];
    const float* b1        = (const float*)d_in[5];
    const float* W2        = (const float*)d_in[6];
    const float* root2     = (const float*)d_in[7];
    const float* b2        = (const float*)d_in[8];
    float* out = (float*)d_out;

    const int* src = edge_idx;
    const int* dst = edge_idx + N_EDGES;

    // workspace layout (byte offsets, 16B aligned), total ~40.8 MB
    char* ws = (char*)d_ws;
    unsigned*      pk_in   = (unsigned*)(ws);                  //  6,400,000
    unsigned*      pk_out  = (unsigned*)(ws + 6400000);        //  6,400,000
    unsigned char* dl      = (unsigned char*)(ws + 12800000);  //  1,600,000
    int*           counts  = (int*)(ws + 14400000);            //    400,384
    int*           rowptr  = (int*)(ws + 14800384);            //    400,016
    unsigned*      YPH1    = (unsigned*)(ws + 15200400);       //  6,400,000
    unsigned*      YPH2    = (unsigned*)(ws + 21600400);       //  6,400,000
    float*         R1      = (float*)(ws + 28000400);          //  6,400,000
    float*         R2      = (float*)(ws + 34400400);          //  6,400,000
    int*           bsum    = (int*)(ws + 40800400);            //        784

    dim3 gK1(NCHUNK + (N_NODES * 16 + 1023) / 1024);   // 256 + 1563
    dim3 gAgg((N_NODES * KC) / 256);                   // 3125 exact

    fused_hist_transform<<<gK1, 1024, 0, stream>>>(
        x, W1, root1, b1, YPH1, R1, dst, counts);
    scan_blocksum<<<NSC, SCB, 0, stream>>>(counts, bsum);
    scan_bsum<<<1, 256, 0, stream>>>(bsum);
    scan_write<<<NSC, SCB, 0, stream>>>(counts, bsum);
    scatter_edges<<<NCHUNK, 1024, 0, stream>>>(src, dst, edge_attr,
                                               counts, pk_in, dl);
    group_edges<<<NBUK, 256, 0, stream>>>(counts, pk_in, dl, pk_out, rowptr);

    aggregate_elu_transform<<<gAgg, 256, 0, stream>>>(
        rowptr, pk_out, (const uint4*)YPH1, R1, W2, root2, b2, YPH2, R2);

    aggregate_logsoftmax<<<gAgg, 256, 0, stream>>>(
        rowptr, pk_out, (const uint4*)YPH2, R2, out);
}

// Round 18
// 206.297 us; speedup vs baseline: 1.0695x; 1.0179x over previous
//
#include <hip/hip_runtime.h>
#include <math.h>

#define N_NODES 100000
#define N_EDGES 1600000
#define KC 8                      // lanes per node in aggregates
#define KSH 3
#define NBUK 391                  // buckets of 256 nodes (dst >> 8)
#define NCHUNK 256                // scatter/hist chunk blocks
#define CPE 6250                  // edges per chunk (256*6250 = 1.6M exact)
#define M_CNT (NBUK * NCHUNK)     // 100096
#define SCB 512
#define NSC ((M_CNT + SCB - 1) / SCB)   // 196
#define WS 52                     // transposed-weight LDS stride (16B-aligned, 2-way max)

#define NTL(p) __builtin_nontemporal_load(p)

// ---------------------------------------------------------------------------
__device__ __forceinline__ unsigned bf16_rne(float x) {
    unsigned u = __float_as_uint(x);
    return (u + 0x7FFFu + ((u >> 16) & 1u)) >> 16;
}

// accumulate 4 packed (bf16,bf16) words with weight uu
__device__ __forceinline__ void acc4(float* acc, uint4 w, float uu) {
    acc[0] += fmaf(uu, __uint_as_float(w.x & 0xFFFF0000u), __uint_as_float(w.x << 16));
    acc[1] += fmaf(uu, __uint_as_float(w.y & 0xFFFF0000u), __uint_as_float(w.y << 16));
    acc[2] += fmaf(uu, __uint_as_float(w.z & 0xFFFF0000u), __uint_as_float(w.z << 16));
    acc[3] += fmaf(uu, __uint_as_float(w.w & 0xFFFF0000u), __uint_as_float(w.w << 16));
}

// accumulate one edge (pk = src | u15<<17) from packed-bf16 Y table
__device__ __forceinline__ void edge_accum(unsigned pk,
                                           const uint4* __restrict__ YPH,
                                           float acc[16]) {
    float uu = (float)(pk >> 17) * (1.0f / 32767.0f);
    const uint4* yp = YPH + (size_t)(pk & 0x1FFFFu) * 4;
    uint4 w0 = yp[0], w1 = yp[1], w2 = yp[2], w3 = yp[3];
    acc4(acc + 0, w0, uu);
    acc4(acc + 4, w1, uu);
    acc4(acc + 8, w2, uu);
    acc4(acc + 12, w3, uu);
}

// two edges, loads grouped ahead of FMAs for MLP
__device__ __forceinline__ void edge_accum2(unsigned p0, unsigned p1,
                                            const uint4* __restrict__ YPH,
                                            float acc[16]) {
    float u0 = (float)(p0 >> 17) * (1.0f / 32767.0f);
    float u1 = (float)(p1 >> 17) * (1.0f / 32767.0f);
    const uint4* a = YPH + (size_t)(p0 & 0x1FFFFu) * 4;
    const uint4* b = YPH + (size_t)(p1 & 0x1FFFFu) * 4;
    uint4 w0 = a[0], w1 = a[1], w2 = a[2], w3 = a[3];
    uint4 v0 = b[0], v1 = b[1], v2 = b[2], v3 = b[3];
    acc4(acc + 0, w0, u0);
    acc4(acc + 4, w1, u0);
    acc4(acc + 8, w2, u0);
    acc4(acc + 12, w3, u0);
    acc4(acc + 0, v0, u1);
    acc4(acc + 4, v1, u1);
    acc4(acc + 8, v2, u1);
    acc4(acc + 12, v3, u1);
}

// ---------------------------------------------------------------------------
// K1 (block = 1024): blocks [0,NCHUNK) histogram dst-buckets (LDS atomics);
// blocks [NCHUNK, NCHUNK+1563) run the layer-1 transform (64 nodes/block).
// Weights stored TRANSPOSED in LDS ([o][f], stride WS) so each thread reads
// float4 chunks (36 ds_read_b128 / thread instead of 144 ds_read_b32).
__global__ __launch_bounds__(1024)
void fused_hist_transform(const float* __restrict__ X,
                          const float* __restrict__ W,
                          const float* __restrict__ root,
                          const float* __restrict__ bias,
                          unsigned* __restrict__ YPH, float* __restrict__ R,
                          const int* __restrict__ dst,
                          int* __restrict__ counts) {
    int t = threadIdx.x;
    if (blockIdx.x < NCHUNK) {
        __shared__ int h[NBUK];
        for (int i = t; i < NBUK; i += 1024) h[i] = 0;
        __syncthreads();
        int c = blockIdx.x;
        const int* dp = dst + c * CPE;
        for (int j = t; j < CPE; j += 1024) atomicAdd(&h[NTL(dp + j) >> 8], 1);
        __syncthreads();
        for (int i = t; i < NBUK; i += 1024) counts[i * NCHUNK + c] = h[i];
    } else {
        __shared__ float sW0[16 * WS];
        __shared__ float sWd[16 * WS];
        __shared__ float sR[16 * WS];
        __shared__ float sB[16];
        int bid = blockIdx.x - NCHUNK;
        for (int i = t; i < 48 * 16; i += 1024) {
            int f = i >> 4, o = i & 15;
            float w0 = W[i];
            float w1 = W[48 * 16 + i];
            sW0[o * WS + f] = w0;
            sWd[o * WS + f] = w1 - w0;
            sR[o * WS + f]  = root[i];
        }
        if (t < 16) sB[t] = bias[t];
        __syncthreads();

        int idx = bid * 1024 + t;
        int n = idx >> 4;
        int o = idx & 15;
        if (n >= N_NODES) return;

        const float4* xr  = (const float4*)(X + (long)n * 48);
        const float4* w0p = (const float4*)(sW0 + o * WS);
        const float4* wdp = (const float4*)(sWd + o * WS);
        const float4* wrp = (const float4*)(sR  + o * WS);
        float a0 = 0.0f, a1 = 0.0f, ar = 0.0f;
#pragma unroll
        for (int fc = 0; fc < 12; ++fc) {
            float4 xv = xr[fc];
            float4 w0 = w0p[fc];
            float4 wd = wdp[fc];
            float4 wr = wrp[fc];
            a0 = fmaf(xv.x, w0.x, a0); a0 = fmaf(xv.y, w0.y, a0);
            a0 = fmaf(xv.z, w0.z, a0); a0 = fmaf(xv.w, w0.w, a0);
            a1 = fmaf(xv.x, wd.x, a1); a1 = fmaf(xv.y, wd.y, a1);
            a1 = fmaf(xv.z, wd.z, a1); a1 = fmaf(xv.w, wd.w, a1);
            ar = fmaf(xv.x, wr.x, ar); ar = fmaf(xv.y, wr.y, ar);
            ar = fmaf(xv.z, wr.z, ar); ar = fmaf(xv.w, wr.w, ar);
        }
        YPH[idx] = bf16_rne(a0) | (bf16_rne(a1) << 16);
        R[idx]   = ar + sB[o];
    }
}

// ---------------------------------------------------------------------------
// Hierarchical exclusive scan of counts[M_CNT] (3 parallel kernels).
__global__ __launch_bounds__(SCB)
void scan_blocksum(const int* __restrict__ a, int* __restrict__ bsum) {
    __shared__ int s[SCB];
    int t = threadIdx.x;
    int i = blockIdx.x * SCB + t;
    s[t] = (i < M_CNT) ? a[i] : 0;
    __syncthreads();
    for (int off = SCB / 2; off > 0; off >>= 1) {
        if (t < off) s[t] += s[t + off];
        __syncthreads();
    }
    if (t == 0) bsum[blockIdx.x] = s[0];
}

__global__ __launch_bounds__(256)
void scan_bsum(int* __restrict__ bsum) {
    __shared__ int s[256];
    int t = threadIdx.x;
    int v = (t < NSC) ? bsum[t] : 0;
    s[t] = v;
    __syncthreads();
    for (int off = 1; off < 256; off <<= 1) {
        int x = (t >= off) ? s[t - off] : 0;
        __syncthreads();
        s[t] += x;
        __syncthreads();
    }
    if (t < NSC) bsum[t] = s[t] - v;  // exclusive
}

__global__ __launch_bounds__(SCB)
void scan_write(int* __restrict__ a, const int* __restrict__ bsum) {
    __shared__ int s[SCB];
    int t = threadIdx.x;
    int i = blockIdx.x * SCB + t;
    int v = (i < M_CNT) ? a[i] : 0;
    s[t] = v;
    __syncthreads();
    for (int off = 1; off < SCB; off <<= 1) {
        int x = (t >= off) ? s[t - off] : 0;
        __syncthreads();
        s[t] += x;
        __syncthreads();
    }
    if (i < M_CNT) a[i] = bsum[blockIdx.x] + s[t] - v;  // exclusive
}

// ---------------------------------------------------------------------------
// K3 (block = 1024): in-LDS counting sort per chunk, then COALESCED writes.
__global__ __launch_bounds__(1024)
void scatter_edges(const int* __restrict__ src, const int* __restrict__ dst,
                   const float* __restrict__ u,
                   const int* __restrict__ offsets,
                   unsigned* __restrict__ pk, unsigned char* __restrict__ dl) {
    __shared__ unsigned upk[CPE];        // unsorted pk
    __shared__ unsigned short ubuk[CPE]; // bucket per edge
    __shared__ unsigned char udl[CPE];   // unsorted dl
    __shared__ unsigned spk[CPE];        // sorted pk
    __shared__ unsigned char sdl[CPE];   // sorted dl
    __shared__ int ls[NBUK + 1];         // local exclusive offsets
    __shared__ int lcur[NBUK];           // local cursors
    __shared__ int gbase[NBUK];          // cur_global[b] - ls[b]
    __shared__ int sc[SCB];              // scan temp (512)

    int t = threadIdx.x, c = blockIdx.x;

    for (int i = t; i < NBUK; i += 1024) lcur[i] = 0;   // lcur doubles as hist
    __syncthreads();
    for (int j = t; j < CPE; j += 1024) {
        int e = c * CPE + j;
        int d = NTL(dst + e);
        float uu = NTL(u + e);
        uu = uu < 0.0f ? 0.0f : (uu > 1.0f ? 1.0f : uu);
        int u15 = (int)fmaf(uu, 32767.0f, 0.5f);
        upk[j] = (unsigned)NTL(src + e) | ((unsigned)u15 << 17);
        udl[j] = (unsigned char)(d & 255);
        int b = d >> 8;
        ubuk[j] = (unsigned short)b;
        atomicAdd(&lcur[b], 1);
    }
    __syncthreads();

    int v = 0;
    if (t < SCB) {
        v = (t < NBUK) ? lcur[t] : 0;
        sc[t] = v;
    }
    __syncthreads();
    for (int off = 1; off < SCB; off <<= 1) {
        int x = 0;
        if (t < SCB && t >= off) x = sc[t - off];
        __syncthreads();
        if (t < SCB) sc[t] += x;
        __syncthreads();
    }
    if (t < NBUK) {
        int ex = sc[t] - v;
        ls[t] = ex;
        lcur[t] = ex;
        gbase[t] = offsets[t * NCHUNK + c] - ex;
    }
    if (t == 0) ls[NBUK] = CPE;
    __syncthreads();

    for (int j = t; j < CPE; j += 1024) {
        int b = ubuk[j];
        int p = atomicAdd(&lcur[b], 1);
        spk[p] = upk[j];
        sdl[p] = udl[j];
    }
    __syncthreads();

    for (int j = t; j < CPE; j += 1024) {
        int lo = 0, hi = NBUK;
        while (hi - lo > 1) {
            int mid = (lo + hi) >> 1;
            if (ls[mid] <= j) lo = mid; else hi = mid;
        }
        int g = gbase[lo] + j;
        pk[g] = spk[j];
        dl[g] = sdl[j];
    }
}

// ---------------------------------------------------------------------------
// K4 (block = 1024): one block per bucket; group edges by node -> dense CSR.
// 4x the waves of the 256-thread version to hide LDS-atomic/gather latency.
__global__ __launch_bounds__(1024)
void group_edges(const int* __restrict__ offsets,
                 const unsigned* __restrict__ pk_in,
                 const unsigned char* __restrict__ dl,
                 unsigned* __restrict__ pk_out,
                 int* __restrict__ rowptr) {
    __shared__ int h[256];
    __shared__ int pre[256];
    int b = blockIdx.x, t = threadIdx.x;
    int beg = offsets[b * NCHUNK];
    int end = (b + 1 < NBUK) ? offsets[(b + 1) * NCHUNK] : N_EDGES;
    if (t < 256) h[t] = 0;
    __syncthreads();
    for (int j = beg + t; j < end; j += 1024) atomicAdd(&h[NTL(dl + j)], 1);
    __syncthreads();
    int cntv = 0;
    if (t < 256) { cntv = h[t]; pre[t] = cntv; }
    __syncthreads();
    for (int off = 1; off < 256; off <<= 1) {
        int x = 0;
        if (t < 256 && t >= off) x = pre[t - off];
        __syncthreads();
        if (t < 256) pre[t] += x;
        __syncthreads();
    }
    if (t < 256) {
        int ex = pre[t] - cntv;   // exclusive local offset of node (b<<8)+t
        int node0 = b << 8;
        if (node0 + t < N_NODES) rowptr[node0 + t] = beg + ex;
        h[t] = ex;                // reuse as cursor
    }
    if (b == 0 && t == 0) rowptr[N_NODES] = N_EDGES;
    __syncthreads();
    for (int j = beg + t; j < end; j += 1024) {
        int loc = dl[j];
        int pos = atomicAdd(&h[loc], 1);
        pk_out[beg + pos] = pk_in[j];
    }
}

// ---------------------------------------------------------------------------
// Aggregate layer 1 + ELU + layer-2 transform fused. KC lanes per node read
// the node's CSR range streamed (nontemporal); butterfly leaves full acc in
// every lane.
__global__ __launch_bounds__(256)
void aggregate_elu_transform(const int* __restrict__ rowptr,
                             const unsigned* __restrict__ csr,
                             const uint4* __restrict__ YPH1,
                             const float* __restrict__ R1,
                             const float* __restrict__ W2,
                             const float* __restrict__ root2,
                             const float* __restrict__ b2,
                             unsigned* __restrict__ YPH2,
                             float* __restrict__ R2) {
    __shared__ float sW0[16 * 16];
    __shared__ float sWd[16 * 16];
    __shared__ float sR[16 * 16];
    __shared__ float sB[16];
    int t = threadIdx.x;
    {
        float w0 = W2[t];
        float w1 = W2[256 + t];
        sW0[t] = w0;
        sWd[t] = w1 - w0;
        sR[t]  = root2[t];
    }
    if (t < 16) sB[t] = b2[t];
    __syncthreads();

    int g = blockIdx.x * 256 + t;
    int n = g >> KSH;
    int h = g & (KC - 1);
    int beg = rowptr[n], end = rowptr[n + 1];
    int deg = end - beg;

    float acc[16];
#pragma unroll
    for (int i = 0; i < 16; ++i) acc[i] = 0.0f;
    int j = beg + h;
    for (; j + KC < end; j += 2 * KC)
        edge_accum2(NTL(csr + j), NTL(csr + j + KC), YPH1, acc);
    if (j < end) edge_accum(NTL(csr + j), YPH1, acc);

#pragma unroll
    for (int mask = 1; mask <= 4; mask <<= 1) {
#pragma unroll
        for (int i = 0; i < 16; ++i) acc[i] += __shfl_xor(acc[i], mask);
    }
    float inv = 1.0f / (deg > 0 ? (float)deg : 1.0f);

    // full H row (ELU'd) in registers
    float h16[16];
    const float4* rp = (const float4*)(R1 + (size_t)n * 16);
#pragma unroll
    for (int q = 0; q < 4; ++q) {
        float4 rr = rp[q];
        float v;
        v = fmaf(acc[4 * q + 0], inv, rr.x); h16[4 * q + 0] = v > 0.0f ? v : expm1f(v);
        v = fmaf(acc[4 * q + 1], inv, rr.y); h16[4 * q + 1] = v > 0.0f ? v : expm1f(v);
        v = fmaf(acc[4 * q + 2], inv, rr.z); h16[4 * q + 2] = v > 0.0f ? v : expm1f(v);
        v = fmaf(acc[4 * q + 3], inv, rr.w); h16[4 * q + 3] = v > 0.0f ? v : expm1f(v);
    }

    // layer-2 transform: this lane's 2 output features o = 2h, 2h+1
    int o0 = 2 * h;
    float a0 = 0.0f, a1 = 0.0f, ar = 0.0f;
    float c0 = 0.0f, c1 = 0.0f, cr = 0.0f;
#pragma unroll
    for (int f = 0; f < 16; ++f) {
        float hv = h16[f];
        a0 = fmaf(hv, sW0[f * 16 + o0], a0);
        a1 = fmaf(hv, sWd[f * 16 + o0], a1);
        ar = fmaf(hv, sR[f * 16 + o0],  ar);
        c0 = fmaf(hv, sW0[f * 16 + o0 + 1], c0);
        c1 = fmaf(hv, sWd[f * 16 + o0 + 1], c1);
        cr = fmaf(hv, sR[f * 16 + o0 + 1],  cr);
    }
    ((uint2*)YPH2)[g] = make_uint2(bf16_rne(a0) | (bf16_rne(a1) << 16),
                                   bf16_rne(c0) | (bf16_rne(c1) << 16));
    ((float2*)R2)[g] = make_float2(ar + sB[o0], cr + sB[o0 + 1]);
}

// ---------------------------------------------------------------------------
// Aggregate layer 2 + log-softmax, CSR streamed (nontemporal).
__global__ __launch_bounds__(256)
void aggregate_logsoftmax(const int* __restrict__ rowptr,
                          const unsigned* __restrict__ csr,
                          const uint4* __restrict__ YPH,
                          const float* __restrict__ R,
                          float* __restrict__ out) {
    int g = blockIdx.x * 256 + threadIdx.x;
    int n = g >> KSH;
    int h = g & (KC - 1);
    int beg = rowptr[n], end = rowptr[n + 1];
    int deg = end - beg;

    float acc[16];
#pragma unroll
    for (int i = 0; i < 16; ++i) acc[i] = 0.0f;
    int j = beg + h;
    for (; j + KC < end; j += 2 * KC)
        edge_accum2(NTL(csr + j), NTL(csr + j + KC), YPH, acc);
    if (j < end) edge_accum(NTL(csr + j), YPH, acc);

#pragma unroll
    for (int mask = 1; mask <= 4; mask <<= 1) {
#pragma unroll
        for (int i = 0; i < 16; ++i) acc[i] += __shfl_xor(acc[i], mask);
    }
    float inv = 1.0f / (deg > 0 ? (float)deg : 1.0f);

    float2 rr = ((const float2*)R)[g];
    float v0 = fmaf(acc[2 * h + 0], inv, rr.x);
    float v1 = fmaf(acc[2 * h + 1], inv, rr.y);

    float m = fmaxf(v0, v1);
#pragma unroll
    for (int mask = 1; mask <= 4; mask <<= 1) m = fmaxf(m, __shfl_xor(m, mask));
    float s = expf(v0 - m) + expf(v1 - m);
#pragma unroll
    for (int mask = 1; mask <= 4; mask <<= 1) s += __shfl_xor(s, mask);
    float lse = m + logf(s);

    ((float2*)out)[g] = make_float2(v0 - lse, v1 - lse);
}

// ---------------------------------------------------------------------------
extern "C" void kernel_launch(void* const* d_in, const int* in_sizes, int n_in,
                              void* d_out, int out_size, void* d_ws, size_t ws_size,
                              hipStream_t stream) {
    const float* x         = (const float*)d_in[0];
    const float* edge_attr = (const float*)d_in[1];
    const int*   edge_idx  = (const int*)d_in[2];
    const float* W1        = (const float*)d_in[3];
    const float* root1     = (const float*)d_in[4];
    const float* b1        = (const float*)d_in[5];
    const float* W2        = (const float*)d_in[6];
    const float* root2     = (const float*)d_in[7];
    const float* b2        = (const float*)d_in[8];
    float* out = (float*)d_out;

    const int* src = edge_idx;
    const int* dst = edge_idx + N_EDGES;

    // workspace layout (byte offsets, 16B aligned), total ~40.8 MB
    char* ws = (char*)d_ws;
    unsigned*      pk_in   = (unsigned*)(ws);                  //  6,400,000
    unsigned*      pk_out  = (unsigned*)(ws + 6400000);        //  6,400,000
    unsigned char* dl      = (unsigned char*)(ws + 12800000);  //  1,600,000
    int*           counts  = (int*)(ws + 14400000);            //    400,384
    int*           rowptr  = (int*)(ws + 14800384);            //    400,016
    unsigned*      YPH1    = (unsigned*)(ws + 15200400);       //  6,400,000
    unsigned*      YPH2    = (unsigned*)(ws + 21600400);       //  6,400,000
    float*         R1      = (float*)(ws + 28000400);          //  6,400,000
    float*         R2      = (float*)(ws + 34400400);          //  6,400,000
    int*           bsum    = (int*)(ws + 40800400);            //        784

    dim3 gK1(NCHUNK + (N_NODES * 16 + 1023) / 1024);   // 256 + 1563
    dim3 gAgg((N_NODES * KC) / 256);                   // 3125 exact

    fused_hist_transform<<<gK1, 1024, 0, stream>>>(
        x, W1, root1, b1, YPH1, R1, dst, counts);
    scan_blocksum<<<NSC, SCB, 0, stream>>>(counts, bsum);
    scan_bsum<<<1, 256, 0, stream>>>(bsum);
    scan_write<<<NSC, SCB, 0, stream>>>(counts, bsum);
    scatter_edges<<<NCHUNK, 1024, 0, stream>>>(src, dst, edge_attr,
                                               counts, pk_in, dl);
    group_edges<<<NBUK, 1024, 0, stream>>>(counts, pk_in, dl, pk_out, rowptr);

    aggregate_elu_transform<<<gAgg, 256, 0, stream>>>(
        rowptr, pk_out, (const uint4*)YPH1, R1, W2, root2, b2, YPH2, R2);

    aggregate_logsoftmax<<<gAgg, 256, 0, stream>>>(
        rowptr, pk_out, (const uint4*)YPH2, R2, out);
}